// Round 4
// baseline (19833.386 us; speedup 1.0000x reference)
//
#include <hip/hip_runtime.h>

typedef short bf16x8 __attribute__((ext_vector_type(8)));
typedef float f32x4  __attribute__((ext_vector_type(4)));
typedef unsigned int u32;
typedef unsigned int u32x4v __attribute__((ext_vector_type(4)));
typedef unsigned long long u64;

constexpr int BB = 64;     // batch
constexpr int TT = 1024;   // seq len
constexpr int DD = 64;     // input dim
constexpr int HH = 512;    // hidden
constexpr int NGRP = 4;    // batch groups (independent)
constexpr int WPG  = 16;   // workgroups per group; WG wid owns k-block kk==wid
constexpr int MB   = 16;   // batch rows per group
constexpr int UPW  = 32;   // hidden units per wg
constexpr int BLOCK = 384; // 6 waves, one 16-col gate tile per wave (R2 structure)

// board: [2][NGRP][WPG(kk)][512] tagged words; word = (tag16<<16) | bf16(h)
// A-frag order within a kk slice: word w = lane*8 + i  ->  row=lane&15, u=(lane>>4)*8+i
constexpr size_t BOARD_BYTES = (size_t)2 * NGRP * WPG * 512 * 4;  // 256 KB

__device__ __forceinline__ short f2bf(float f) {
    unsigned u = __builtin_bit_cast(unsigned, f);
    u = (u + 0x7FFFu + ((u >> 16) & 1u)) >> 16;   // round-to-nearest-even
    return (short)u;
}
__device__ __forceinline__ float bf2f(short s) {
    unsigned u = ((unsigned)(unsigned short)s) << 16;
    return __builtin_bit_cast(float, u);
}

__global__ __launch_bounds__(BLOCK, 2)
void gru_persistent(const float* __restrict__ x,
                    const float* __restrict__ h0,
                    const float* __restrict__ w_ih,
                    const float* __restrict__ w_hh,
                    const float* __restrict__ fc_w,
                    const float* __restrict__ fc_b,
                    float* __restrict__ out,
                    u32* __restrict__ board)
{
    const int wg   = blockIdx.x;     // 0..63
    const int gb   = wg >> 4;        // batch group 0..3
    const int wid  = wg & 15;        // unit-wg 0..15 (owns k-block kk == wid)
    const int tid  = threadIdx.x;
    const int wave = tid >> 6;       // 0..5
    const int lane = tid & 63;
    const int l15  = lane & 15;
    const int lhi  = lane >> 4;      // 0..3
    const int u0   = wid * UPW;

    // wave's 16 gate columns (local cols [16*wave,16*wave+16) of 96 = r|z|n x 32)
    const int cloc = wave * 16 + l15;       // 0..95
    const int gate = cloc >> 5;             // 0=r 1=z 2=n
    const int uloc = cloc & 31;
    const int grow = gate * HH + u0 + uloc; // row of w_hh / w_ih

    __shared__ float lds_gi[16][100];
    __shared__ float lds_gh[16][100];
    __shared__ float hprev[512];   // f32 h for this wg's units: [uu*16+row]
    __shared__ float pacc[512];
    __shared__ float fcw_s[UPW];

    // ---- register-resident weights as MFMA B-frags, bf16 hi/lo split ----
    // B-frag layout for 16x16x32: col = lane&15, k = (lane>>4)*8 + i
    bf16x8 whh_hi[16], whh_lo[16];
#pragma unroll
    for (int kk = 0; kk < 16; ++kk) {
        const float* src = w_hh + (size_t)grow * HH + kk * 32 + lhi * 8;
        bf16x8 hi, lo;
#pragma unroll
        for (int i = 0; i < 8; ++i) {
            float w = src[i];
            short h16 = f2bf(w);
            hi[i] = h16; lo[i] = f2bf(w - bf2f(h16));
        }
        whh_hi[kk] = hi; whh_lo[kk] = lo;
    }
    bf16x8 wih_hi[2], wih_lo[2];
#pragma unroll
    for (int kk = 0; kk < 2; ++kk) {
        const float* src = w_ih + (size_t)grow * DD + kk * 32 + lhi * 8;
        bf16x8 hi, lo;
#pragma unroll
        for (int i = 0; i < 8; ++i) {
            float w = src[i];
            short h16 = f2bf(w);
            hi[i] = h16; lo[i] = f2bf(w - bf2f(h16));
        }
        wih_hi[kk] = hi; wih_lo[kk] = lo;
    }

    if (tid < UPW) fcw_s[tid] = fc_w[u0 + tid];
    const float fcb = fc_b[0];

    // ---- init: hprev (f32) + board buf0 tagged words (tag = 1) ----
    for (int idx2 = tid; idx2 < 256; idx2 += BLOCK) {
        int row = idx2 & 15, up = idx2 >> 4;       // up 0..15 -> units 2up, 2up+1
        int uu0 = up * 2, uu1 = uu0 + 1;
        float ha = h0[(size_t)(gb * MB + row) * HH + (u0 + uu0)];
        float hb = h0[(size_t)(gb * MB + row) * HH + (u0 + uu1)];
        hprev[uu0 * 16 + row] = ha;
        hprev[uu1 * 16 + row] = hb;
        u32 wa = (1u << 16) | (u32)(unsigned short)f2bf(ha);
        u32 wb = (1u << 16) | (u32)(unsigned short)f2bf(hb);
        u64* bq = (u64*)board
                + ((size_t)(0 * NGRP + gb) * WPG + wid) * 256
                + ((up >> 2) * 16 + row) * 4 + (up & 3);
        __hip_atomic_store(bq, (u64)wa | ((u64)wb << 32),
                           __ATOMIC_RELAXED, __HIP_MEMORY_SCOPE_AGENT);
    }
    __syncthreads();

    const float* xrow = x + ((size_t)(gb * MB + l15) * TT) * DD + lhi * 8;

    for (int t = 0; t < TT; ++t) {
        const int rbuf = t & 1, wbuf = rbuf ^ 1;

        // ---- gi = x_t @ w_ih^T : independent of h, overlaps board latency ----
        f32x4 acc_gi = {0.f, 0.f, 0.f, 0.f};
#pragma unroll
        for (int kk = 0; kk < 2; ++kk) {
            const float* xs = xrow + (size_t)t * DD + kk * 32;
            const float4 v0 = *(const float4*)(xs);
            const float4 v1 = *(const float4*)(xs + 4);
            bf16x8 a;
            a[0] = f2bf(v0.x); a[1] = f2bf(v0.y); a[2] = f2bf(v0.z); a[3] = f2bf(v0.w);
            a[4] = f2bf(v1.x); a[5] = f2bf(v1.y); a[6] = f2bf(v1.z); a[7] = f2bf(v1.w);
            acc_gi = __builtin_amdgcn_mfma_f32_16x16x32_bf16(a, wih_hi[kk], acc_gi, 0, 0, 0);
            acc_gi = __builtin_amdgcn_mfma_f32_16x16x32_bf16(a, wih_lo[kk], acc_gi, 0, 0, 0);
        }

        // ---- speculative tagged board read, gh MFMAs folded into retry body ----
        // (retries are rare in steady state; on mismatch we redo the MFMAs)
        const u32 expTag = (u32)(t + 1) << 16;
        const u64* bq = (const u64*)board
                      + ((size_t)(rbuf * NGRP + gb) * WPG) * 256 + lane * 4;
        f32x4 acc_gh;
        u32 mism;
        do {
            mism = 0;
            acc_gh[0] = 0.f; acc_gh[1] = 0.f; acc_gh[2] = 0.f; acc_gh[3] = 0.f;
#pragma unroll
            for (int kk = 0; kk < 16; ++kk) {
                const u64* p = bq + (size_t)kk * 256;
                u64 v0 = __hip_atomic_load(p + 0, __ATOMIC_RELAXED, __HIP_MEMORY_SCOPE_AGENT);
                u64 v1 = __hip_atomic_load(p + 1, __ATOMIC_RELAXED, __HIP_MEMORY_SCOPE_AGENT);
                u64 v2 = __hip_atomic_load(p + 2, __ATOMIC_RELAXED, __HIP_MEMORY_SCOPE_AGENT);
                u64 v3 = __hip_atomic_load(p + 3, __ATOMIC_RELAXED, __HIP_MEMORY_SCOPE_AGENT);
                u32 w0 = (u32)v0, w1 = (u32)(v0 >> 32);
                u32 w2 = (u32)v1, w3 = (u32)(v1 >> 32);
                u32 w4 = (u32)v2, w5 = (u32)(v2 >> 32);
                u32 w6 = (u32)v3, w7 = (u32)(v3 >> 32);
                mism |= (w0 ^ expTag) & 0xFFFF0000u;
                mism |= (w1 ^ expTag) & 0xFFFF0000u;
                mism |= (w2 ^ expTag) & 0xFFFF0000u;
                mism |= (w3 ^ expTag) & 0xFFFF0000u;
                mism |= (w4 ^ expTag) & 0xFFFF0000u;
                mism |= (w5 ^ expTag) & 0xFFFF0000u;
                mism |= (w6 ^ expTag) & 0xFFFF0000u;
                mism |= (w7 ^ expTag) & 0xFFFF0000u;
                u32x4v d;
                d.x = __builtin_amdgcn_perm(w1, w0, 0x05040100u);  // [w0.lo16|w1.lo16]
                d.y = __builtin_amdgcn_perm(w3, w2, 0x05040100u);
                d.z = __builtin_amdgcn_perm(w5, w4, 0x05040100u);
                d.w = __builtin_amdgcn_perm(w7, w6, 0x05040100u);
                bf16x8 hfk = __builtin_bit_cast(bf16x8, d);
                acc_gh = __builtin_amdgcn_mfma_f32_16x16x32_bf16(hfk, whh_hi[kk], acc_gh, 0, 0, 0);
                acc_gh = __builtin_amdgcn_mfma_f32_16x16x32_bf16(hfk, whh_lo[kk], acc_gh, 0, 0, 0);
            }
        } while (__any(mism != 0));

        // C/D layout: col = lane&15 (-> gate col cloc), row = lhi*4 + j
#pragma unroll
        for (int j = 0; j < 4; ++j) {
            int row = lhi * 4 + j;
            lds_gi[row][cloc] = acc_gi[j];
            lds_gh[row][cloc] = acc_gh[j];
        }
        __syncthreads();

        // ---- gates + h update + immediate tagged publish (2 units/thread) ----
        const u32 tagNew = (u32)(t + 2) << 16;
        for (int idx2 = tid; idx2 < 256; idx2 += BLOCK) {
            int row = idx2 & 15, up = idx2 >> 4;
            int uu0 = up * 2, uu1 = uu0 + 1;
            float hn01[2];
#pragma unroll
            for (int q = 0; q < 2; ++q) {
                int uu = uu0 + q;
                float gr  = lds_gi[row][uu]      + lds_gh[row][uu];
                float gz  = lds_gi[row][32 + uu] + lds_gh[row][32 + uu];
                float gin = lds_gi[row][64 + uu];
                float ghn = lds_gh[row][64 + uu];
                float r = 1.f / (1.f + __expf(-gr));
                float z = 1.f / (1.f + __expf(-gz));
                float v = gin + r * ghn;
                v = fminf(15.f, fmaxf(-15.f, v));
                float e2 = __expf(-2.f * v);
                float n = (1.f - e2) / (1.f + e2);           // tanh(v)
                hn01[q] = (1.f - z) * n + z * hprev[uu * 16 + row];
            }
            // publish FIRST (critical path for the other 15 WGs in the group)
            u32 wa = tagNew | (u32)(unsigned short)f2bf(hn01[0]);
            u32 wb = tagNew | (u32)(unsigned short)f2bf(hn01[1]);
            u64* bw = (u64*)board
                    + ((size_t)(wbuf * NGRP + gb) * WPG + wid) * 256
                    + ((up >> 2) * 16 + row) * 4 + (up & 3);
            __hip_atomic_store(bw, (u64)wa | ((u64)wb << 32),
                               __ATOMIC_RELAXED, __HIP_MEMORY_SCOPE_AGENT);
            // off-critical-path bookkeeping
            hprev[uu0 * 16 + row] = hn01[0];
            hprev[uu1 * 16 + row] = hn01[1];
            pacc[uu0 * 16 + row] = fmaxf(hn01[0], 0.f) * fcw_s[uu0];
            pacc[uu1 * 16 + row] = fmaxf(hn01[1], 0.f) * fcw_s[uu1];
            if (t == TT - 1) {
                out[(size_t)BB * TT + (size_t)(gb * MB + row) * HH + (u0 + uu0)] = hn01[0];
                out[(size_t)BB * TT + (size_t)(gb * MB + row) * HH + (u0 + uu1)] = hn01[1];
            }
        }
        __syncthreads();

        if (tid < MB) {
            float s = (wid == 0) ? fcb : 0.f;
#pragma unroll
            for (int uu = 0; uu < UPW; ++uu) s += pacc[uu * 16 + tid];
            atomicAdd(&out[(size_t)(gb * MB + tid) * TT + t], s);
        }
    }
}

extern "C" void kernel_launch(void* const* d_in, const int* in_sizes, int n_in,
                              void* d_out, int out_size, void* d_ws, size_t ws_size,
                              hipStream_t stream)
{
    const float* x    = (const float*)d_in[0];
    const float* h0   = (const float*)d_in[1];
    const float* w_ih = (const float*)d_in[2];
    const float* w_hh = (const float*)d_in[3];
    const float* fc_w = (const float*)d_in[4];
    const float* fc_b = (const float*)d_in[5];
    float* out = (float*)d_out;
    u32* board = (u32*)d_ws;

    // zero the atomically-accumulated out region; clear board tags so every
    // replay re-synchronizes from scratch (stale tag 1024 would collide with a
    // live expected tag near the end of the next replay otherwise)
    hipMemsetAsync(d_out, 0, (size_t)BB * TT * sizeof(float), stream);
    hipMemsetAsync(d_ws, 0, BOARD_BYTES, stream);

    void* args[] = { (void*)&x, (void*)&h0, (void*)&w_ih, (void*)&w_hh,
                     (void*)&fc_w, (void*)&fc_b, (void*)&out, (void*)&board };
    hipError_t err = hipLaunchCooperativeKernel((void*)gru_persistent,
                                                dim3(NGRP * WPG), dim3(BLOCK),
                                                args, 0, stream);
    if (err != hipSuccess) {
        (void)hipGetLastError();  // clear sticky error, then plain launch:
        // 64 blocks at >=1 block/CU occupancy are co-resident on 256 CUs anyway
        gru_persistent<<<dim3(NGRP * WPG), dim3(BLOCK), 0, stream>>>(
            x, h0, w_ih, w_hh, fc_w, fc_b, out, board);
    }
}

// Round 7
// 3471.927 us; speedup vs baseline: 5.7125x; 5.7125x over previous
//
#include <hip/hip_runtime.h>

typedef short bf16x8 __attribute__((ext_vector_type(8)));
typedef float f32x4  __attribute__((ext_vector_type(4)));
typedef unsigned int u32;
typedef unsigned long long u64;

constexpr int BB = 64;     // batch
constexpr int TT = 1024;   // seq len
constexpr int DD = 64;     // input dim
constexpr int HH = 512;    // hidden
constexpr int NGRP = 4;    // batch groups (independent)
constexpr int WPG  = 16;   // workgroups per group; WG wid owns units [wid*32, wid*32+32)
constexpr int MB   = 16;   // batch rows per group
constexpr int UPW  = 32;   // hidden units per wg
constexpr int BLOCK = 384; // 6 waves, one 16-col gate tile per wave

// tagged board: [2][NGRP][row 16][pair 256] u64; each u64 = two tagged words
// word = (tag16 << 16) | bf16(h);  pair p covers units (2p, 2p+1)
constexpr size_t SLAB_U64  = (size_t)MB * 256;            // 4096 u64 per (buf,grp)
constexpr size_t BOARD_U64 = 2 * NGRP * SLAB_U64;         // 32768 u64
constexpr size_t BOARD_B   = BOARD_U64 * 8;               // 256 KB

__device__ __forceinline__ short f2bf(float f) {
    unsigned u = __builtin_bit_cast(unsigned, f);
    u = (u + 0x7FFFu + ((u >> 16) & 1u)) >> 16;   // round-to-nearest-even
    return (short)u;
}
__device__ __forceinline__ float bf2f(short s) {
    unsigned u = ((unsigned)(unsigned short)s) << 16;
    return __builtin_bit_cast(float, u);
}

// LDS board layout: [kk 16][row 16][80B] (64B data = 32 units bf16, 16B pad)
constexpr int LKK = 1296;  // kk stride bytes (16*80 + 16 extra pad)
constexpr int LROW = 80;

__global__ __launch_bounds__(BLOCK, 2)
void gru_persistent(const float* __restrict__ x,
                    const float* __restrict__ h0,
                    const float* __restrict__ w_ih,
                    const float* __restrict__ w_hh,
                    const float* __restrict__ fc_w,
                    const float* __restrict__ fc_b,
                    float* __restrict__ out,
                    u64* __restrict__ board)
{
    const int wg   = blockIdx.x;     // 0..63
    const int gb   = wg >> 4;        // batch group 0..3
    const int wid  = wg & 15;        // unit-wg 0..15
    const int tid  = threadIdx.x;
    const int wave = tid >> 6;       // 0..5
    const int lane = tid & 63;
    const int l15  = lane & 15;
    const int lhi  = lane >> 4;      // 0..3
    const int u0   = wid * UPW;

    // wave owns gate cols [wave*16, wave*16+16) of 96 = r|z|n x 32
    const int cloc = wave * 16 + l15;
    const int grow = (cloc >> 5) * HH + u0 + (cloc & 31);

    __shared__ char  lds_board[16 * LKK];   // A-operand staging
    __shared__ float lds_gi[16][100];
    __shared__ float lds_gh[16][100];
    __shared__ float pacc[512];
    __shared__ float fcw_s[UPW];

    // ---- register-resident weights as MFMA B-frags, bf16 hi/lo split ----
    bf16x8 whh_hi[16], whh_lo[16];
#pragma unroll
    for (int kk = 0; kk < 16; ++kk) {
        const float* src = w_hh + (size_t)grow * HH + kk * 32 + lhi * 8;
        bf16x8 hi, lo;
#pragma unroll
        for (int i = 0; i < 8; ++i) {
            float w = src[i];
            short h16 = f2bf(w);
            hi[i] = h16; lo[i] = f2bf(w - bf2f(h16));
        }
        whh_hi[kk] = hi; whh_lo[kk] = lo;
    }
    bf16x8 wih_hi[2], wih_lo[2];
#pragma unroll
    for (int kk = 0; kk < 2; ++kk) {
        const float* src = w_ih + (size_t)grow * DD + kk * 32 + lhi * 8;
        bf16x8 hi, lo;
#pragma unroll
        for (int i = 0; i < 8; ++i) {
            float w = src[i];
            short h16 = f2bf(w);
            hi[i] = h16; lo[i] = f2bf(w - bf2f(h16));
        }
        wih_hi[kk] = hi; wih_lo[kk] = lo;
    }

    if (tid < UPW) fcw_s[tid] = fc_w[u0 + tid];
    const float fcb = fc_b[0];

    // ---- init: hreg (2 f32/thread) + board buf0 tagged (tag=1) ----
    // producer thread (tid<256): row = tid>>4, local pair lp = tid&15
    float hreg0 = 0.f, hreg1 = 0.f;
    if (tid < 256) {
        int row = tid >> 4, lp = tid & 15;
        int uu0 = 2 * lp, uu1 = uu0 + 1;
        hreg0 = h0[(size_t)(gb * MB + row) * HH + (u0 + uu0)];
        hreg1 = h0[(size_t)(gb * MB + row) * HH + (u0 + uu1)];
        u32 wa = (1u << 16) | (u32)(unsigned short)f2bf(hreg0);
        u32 wb = (1u << 16) | (u32)(unsigned short)f2bf(hreg1);
        u64* bw = board + (size_t)(0 * NGRP + gb) * SLAB_U64
                + row * 256 + (wid * 16 + lp);
        __hip_atomic_store(bw, (u64)wa | ((u64)wb << 32),
                           __ATOMIC_RELAXED, __HIP_MEMORY_SCOPE_AGENT);
        // no drain, no flag: the tag travels with the data
    }
    __syncthreads();

    const float* xrow = x + ((size_t)(gb * MB + l15) * TT) * DD + lhi * 8;

    for (int t = 0; t < TT; ++t) {
        const int rbuf = t & 1, wbuf = rbuf ^ 1;

        // (a) gi = x_t @ w_ih^T : independent of h, overlaps board latency
        f32x4 gi_hi = {0.f,0.f,0.f,0.f}, gi_lo = {0.f,0.f,0.f,0.f};
#pragma unroll
        for (int kk = 0; kk < 2; ++kk) {
            const float* xs = xrow + (size_t)t * DD + kk * 32;
            const float4 v0 = *(const float4*)(xs);
            const float4 v1 = *(const float4*)(xs + 4);
            bf16x8 a;
            a[0] = f2bf(v0.x); a[1] = f2bf(v0.y); a[2] = f2bf(v0.z); a[3] = f2bf(v0.w);
            a[4] = f2bf(v1.x); a[5] = f2bf(v1.y); a[6] = f2bf(v1.z); a[7] = f2bf(v1.w);
            gi_hi = __builtin_amdgcn_mfma_f32_16x16x32_bf16(a, wih_hi[kk], gi_hi, 0, 0, 0);
            gi_lo = __builtin_amdgcn_mfma_f32_16x16x32_bf16(a, wih_lo[kk], gi_lo, 0, 0, 0);
        }
        f32x4 acc_gi = gi_hi + gi_lo;

        // (b) single-round-trip tagged read: thread tid<256 owns pair=tid,
        //     one u64 per row; re-load only pending rows until tags match.
        if (tid < 256) {
            const u32 expTag = (u32)(t + 1) << 16;
            const u64* sp = board + (size_t)(rbuf * NGRP + gb) * SLAB_U64 + tid;
            u64 v[16];
            u32 pend = 0xFFFFu;
            do {
#pragma unroll
                for (int i = 0; i < 16; ++i)
                    if (pend & (1u << i))
                        v[i] = __hip_atomic_load(sp + (size_t)i * 256,
                                                 __ATOMIC_RELAXED, __HIP_MEMORY_SCOPE_AGENT);
                u32 np = 0;
#pragma unroll
                for (int i = 0; i < 16; ++i)
                    if (pend & (1u << i)) {
                        u32 lo = (u32)v[i], hi = (u32)(v[i] >> 32);
                        u32 bad = ((lo ^ expTag) | (hi ^ expTag)) & 0xFFFF0000u;
                        np |= bad ? (1u << i) : 0u;
                    }
                pend = np;
            } while (__any(pend != 0));
            // unpack to LDS: [kk = tid>>4][row i][u32 at (tid&15)*4]
            char* lb = lds_board + (tid >> 4) * LKK + (tid & 15) * 4;
#pragma unroll
            for (int i = 0; i < 16; ++i) {
                u32 d = __builtin_amdgcn_perm((u32)(v[i] >> 32), (u32)v[i], 0x05040100u);
                *(u32*)(lb + i * LROW) = d;
            }
        }
        __syncthreads();

        // (c) gh MFMAs from LDS A-frags; hi/lo chains split for latency
        f32x4 gh_hi = {0.f,0.f,0.f,0.f}, gh_lo = {0.f,0.f,0.f,0.f};
        {
            const char* la = lds_board + l15 * LROW + lhi * 16;
#pragma unroll
            for (int kk = 0; kk < 16; ++kk) {
                bf16x8 a = *(const bf16x8*)(la + kk * LKK);
                gh_hi = __builtin_amdgcn_mfma_f32_16x16x32_bf16(a, whh_hi[kk], gh_hi, 0, 0, 0);
                gh_lo = __builtin_amdgcn_mfma_f32_16x16x32_bf16(a, whh_lo[kk], gh_lo, 0, 0, 0);
            }
        }
        f32x4 acc_gh = gh_hi + gh_lo;

        // (d) C/D -> LDS: col = lane&15 (gate col cloc), row = lhi*4 + j
#pragma unroll
        for (int j = 0; j < 4; ++j) {
            int row = lhi * 4 + j;
            lds_gi[row][cloc] = acc_gi[j];
            lds_gh[row][cloc] = acc_gh[j];
        }
        __syncthreads();

        // (e) gates + h update + immediate tagged publish (2 units/thread)
        if (tid < 256) {
            const u32 tagNew = (u32)(t + 2) << 16;
            int row = tid >> 4, lp = tid & 15;
            int uu0 = 2 * lp, uu1 = uu0 + 1;
            float hn01[2];
            float hp[2] = {hreg0, hreg1};
#pragma unroll
            for (int q = 0; q < 2; ++q) {
                int uu = uu0 + q;
                float gr  = lds_gi[row][uu]      + lds_gh[row][uu];
                float gz  = lds_gi[row][32 + uu] + lds_gh[row][32 + uu];
                float gin = lds_gi[row][64 + uu];
                float ghn = lds_gh[row][64 + uu];
                float r = 1.f / (1.f + __expf(-gr));
                float z = 1.f / (1.f + __expf(-gz));
                float v = gin + r * ghn;
                v = fminf(15.f, fmaxf(-15.f, v));
                float e2 = __expf(-2.f * v);
                float n = (1.f - e2) / (1.f + e2);           // tanh(v)
                hn01[q] = (1.f - z) * n + z * hp[q];
            }
            hreg0 = hn01[0]; hreg1 = hn01[1];
            // publish FIRST (critical path for the 15 peers)
            u32 wa = tagNew | (u32)(unsigned short)f2bf(hn01[0]);
            u32 wb = tagNew | (u32)(unsigned short)f2bf(hn01[1]);
            u64* bw = board + (size_t)(wbuf * NGRP + gb) * SLAB_U64
                    + row * 256 + (wid * 16 + lp);
            __hip_atomic_store(bw, (u64)wa | ((u64)wb << 32),
                               __ATOMIC_RELAXED, __HIP_MEMORY_SCOPE_AGENT);
            // off-critical-path bookkeeping
            pacc[row * 32 + uu0] = fmaxf(hn01[0], 0.f) * fcw_s[uu0];
            pacc[row * 32 + uu1] = fmaxf(hn01[1], 0.f) * fcw_s[uu1];
            if (t == TT - 1) {
                out[(size_t)BB * TT + (size_t)(gb * MB + row) * HH + (u0 + uu0)] = hn01[0];
                out[(size_t)BB * TT + (size_t)(gb * MB + row) * HH + (u0 + uu1)] = hn01[1];
            }
        }
        __syncthreads();

        // (f) fc partial reduction, off the recurrence critical path
        if (tid < MB) {
            float s = (wid == 0) ? fcb : 0.f;
#pragma unroll
            for (int uu = 0; uu < UPW; ++uu) s += pacc[tid * 32 + uu];
            atomicAdd(&out[(size_t)(gb * MB + tid) * TT + t], s);
        }
    }
}

extern "C" void kernel_launch(void* const* d_in, const int* in_sizes, int n_in,
                              void* d_out, int out_size, void* d_ws, size_t ws_size,
                              hipStream_t stream)
{
    const float* x    = (const float*)d_in[0];
    const float* h0   = (const float*)d_in[1];
    const float* w_ih = (const float*)d_in[2];
    const float* w_hh = (const float*)d_in[3];
    const float* fc_w = (const float*)d_in[4];
    const float* fc_b = (const float*)d_in[5];
    float* out = (float*)d_out;
    u64* board = (u64*)d_ws;

    // zero the atomically-accumulated out region; clear board tags so every
    // replay re-synchronizes from scratch (tags are the whole protocol)
    hipMemsetAsync(d_out, 0, (size_t)BB * TT * sizeof(float), stream);
    hipMemsetAsync(d_ws, 0, BOARD_B, stream);

    void* args[] = { (void*)&x, (void*)&h0, (void*)&w_ih, (void*)&w_hh,
                     (void*)&fc_w, (void*)&fc_b, (void*)&out, (void*)&board };
    hipError_t err = hipLaunchCooperativeKernel((void*)gru_persistent,
                                                dim3(NGRP * WPG), dim3(BLOCK),
                                                args, 0, stream);
    if (err != hipSuccess) {
        (void)hipGetLastError();  // clear sticky error; plain launch (64 blocks
        // at 2 blocks/CU occupancy are trivially co-resident on 256 CUs)
        gru_persistent<<<dim3(NGRP * WPG), dim3(BLOCK), 0, stream>>>(
            x, h0, w_ih, w_hh, fc_w, fc_b, out, board);
    }
}